// Round 1
// baseline (1158.044 us; speedup 1.0000x reference)
//
#include <hip/hip_runtime.h>

// 3x3 valid conv (NCHW/OIHW) + bias + relu(y)*min(y+3,6)/6, fp32.
// x: (N=4096, C=3, 32, 32), w: (16, 3, 3, 3), out: (N, 16, 30, 30).
// One block per image: 12 KB image tile in LDS, weights transposed to
// [pos][oc] so the hot loop reads them as float4 broadcasts.
// Each thread computes 4 pixels (p = tid + k*256) x 16 output channels.

__global__ __launch_bounds__(256) void conv3x3_hswish(
    const float* __restrict__ x,
    const float* __restrict__ w,
    const float* __restrict__ bias,
    float* __restrict__ out)
{
    const int n = blockIdx.x;
    const int tid = threadIdx.x;

    __shared__ __align__(16) float sx[3 * 32 * 32];  // 12 KB image
    __shared__ __align__(16) float sw[27 * 16];      // [pos][oc]
    __shared__ float sb[16];

    // Stage input image (3072 floats) with float4 loads: 3 per thread.
    {
        const float4* xg = (const float4*)(x + (size_t)n * 3072);
        float4* s4 = (float4*)sx;
        #pragma unroll
        for (int i = 0; i < 3; ++i)
            s4[tid + i * 256] = xg[tid + i * 256];
    }
    // Stage weights transposed: sw[pos*16 + oc] = w[oc*27 + pos].
    for (int i = tid; i < 432; i += 256) {
        int oc = i / 27;
        int pos = i - oc * 27;
        sw[pos * 16 + oc] = w[i];
    }
    if (tid < 16) sb[tid] = bias[tid];
    __syncthreads();

    // Pixel assignment: p = tid + k*256 (flattened oh*30+ow), k = 0..3.
    // 900 pixels/image; dead slots clamp their reads and skip the store.
    int xbase[4];
    int pp[4];
    #pragma unroll
    for (int k = 0; k < 4; ++k) {
        int p = tid + k * 256;
        pp[k] = p;
        int pc = p < 900 ? p : 899;
        int oh = pc / 30;
        int ow = pc - oh * 30;
        xbase[k] = oh * 32 + ow;
    }

    float a[4][16];
    #pragma unroll
    for (int k = 0; k < 4; ++k)
        #pragma unroll
        for (int oc = 0; oc < 16; ++oc) a[k][oc] = 0.f;

    #pragma unroll
    for (int ic = 0; ic < 3; ++ic) {
        #pragma unroll
        for (int kh = 0; kh < 3; ++kh) {
            #pragma unroll
            for (int kw = 0; kw < 3; ++kw) {
                const int pos = (ic * 3 + kh) * 3 + kw;
                const float4* wv = (const float4*)&sw[pos * 16];
                const float4 w0 = wv[0];
                const float4 w1 = wv[1];
                const float4 w2 = wv[2];
                const float4 w3 = wv[3];
                #pragma unroll
                for (int k = 0; k < 4; ++k) {
                    const float xv = sx[ic * 1024 + xbase[k] + kh * 32 + kw];
                    a[k][0]  = fmaf(xv, w0.x, a[k][0]);
                    a[k][1]  = fmaf(xv, w0.y, a[k][1]);
                    a[k][2]  = fmaf(xv, w0.z, a[k][2]);
                    a[k][3]  = fmaf(xv, w0.w, a[k][3]);
                    a[k][4]  = fmaf(xv, w1.x, a[k][4]);
                    a[k][5]  = fmaf(xv, w1.y, a[k][5]);
                    a[k][6]  = fmaf(xv, w1.z, a[k][6]);
                    a[k][7]  = fmaf(xv, w1.w, a[k][7]);
                    a[k][8]  = fmaf(xv, w2.x, a[k][8]);
                    a[k][9]  = fmaf(xv, w2.y, a[k][9]);
                    a[k][10] = fmaf(xv, w2.z, a[k][10]);
                    a[k][11] = fmaf(xv, w2.w, a[k][11]);
                    a[k][12] = fmaf(xv, w3.x, a[k][12]);
                    a[k][13] = fmaf(xv, w3.y, a[k][13]);
                    a[k][14] = fmaf(xv, w3.z, a[k][14]);
                    a[k][15] = fmaf(xv, w3.w, a[k][15]);
                }
            }
        }
    }

    float* outn = out + (size_t)n * 16 * 900;
    float b0[16];
    #pragma unroll
    for (int oc = 0; oc < 16; ++oc) b0[oc] = sb[oc];

    #pragma unroll
    for (int k = 0; k < 4; ++k) {
        if (pp[k] < 900) {
            #pragma unroll
            for (int oc = 0; oc < 16; ++oc) {
                const float y = a[k][oc] + b0[oc];
                const float r = fmaxf(y, 0.f) * fminf(y + 3.f, 6.f) * (1.f / 6.f);
                outn[oc * 900 + pp[k]] = r;
            }
        }
    }
}

extern "C" void kernel_launch(void* const* d_in, const int* in_sizes, int n_in,
                              void* d_out, int out_size, void* d_ws, size_t ws_size,
                              hipStream_t stream) {
    const float* x    = (const float*)d_in[0];
    const float* w    = (const float*)d_in[1];
    const float* bias = (const float*)d_in[2];
    float* out        = (float*)d_out;

    const int N = in_sizes[0] / (3 * 32 * 32);  // 4096
    conv3x3_hswish<<<N, 256, 0, stream>>>(x, w, bias, out);
}

// Round 2
// 312.264 us; speedup vs baseline: 3.7085x; 3.7085x over previous
//
#include <hip/hip_runtime.h>

// 3x3 valid conv (NCHW/OIHW) + bias + relu(y)*min(y+3,6)/6, fp32.
// x: (N=4096, C=3, 32, 32), w: (16, 3, 3, 3), out: (N, 16, 30, 30).
//
// Round 2 design:
//  - prep kernel transposes weights to wt[pos][oc] (contiguous per position)
//    + bias into d_ws, so the main loop reads them at WAVE-UNIFORM addresses
//    -> compiler emits s_load (SGPRs, SMEM pipe). Zero VGPR cost for weights.
//  - main kernel: one block (256 thr) per image, 12 KB image in LDS.
//    Pixel groups k=0..3 processed SEQUENTIALLY with only 16 live
//    accumulators -> ~40 VGPRs, no spill (round-1 failure mode was
//    VGPR=256 + 3 GB of scratch spill traffic).

__global__ void prep_weights(const float* __restrict__ w,
                             const float* __restrict__ bias,
                             float* __restrict__ wt) {
    const int i = threadIdx.x;
    if (i < 432) {
        const int oc = i / 27;
        const int pos = i - oc * 27;
        wt[pos * 16 + oc] = w[i];          // wt[27][16]
    }
    if (i < 16) wt[432 + i] = bias[i];
}

__global__ __launch_bounds__(256) void conv3x3_hswish(
    const float* __restrict__ x,
    const float* __restrict__ wt,   // [27][16] weights, then [16] bias
    float* __restrict__ out)
{
    const int n = blockIdx.x;
    const int tid = threadIdx.x;

    __shared__ __align__(16) float sx[3 * 32 * 32];  // 12 KB image

    // Stage input image (3072 floats) with float4 loads: 3 per thread.
    {
        const float4* xg = (const float4*)(x + (size_t)n * 3072);
        float4* s4 = (float4*)sx;
        #pragma unroll
        for (int i = 0; i < 3; ++i)
            s4[tid + i * 256] = xg[tid + i * 256];
    }
    __syncthreads();

    float* outn = out + (size_t)n * 16 * 900;

    // Bias: uniform loads -> SGPRs.
    float bv[16];
    #pragma unroll
    for (int oc = 0; oc < 16; ++oc) bv[oc] = wt[432 + oc];

    // 900 pixels / image, 256 threads, 4 sequential passes.
    for (int k = 0; k < 4; ++k) {
        const int p = tid + k * 256;
        const bool active = (p < 900);
        const int pc = active ? p : 899;
        const int oh = pc / 30;
        const int ow = pc - oh * 30;
        const int xb = oh * 32 + ow;

        float acc[16];
        #pragma unroll
        for (int oc = 0; oc < 16; ++oc) acc[oc] = bv[oc];

        #pragma unroll
        for (int ic = 0; ic < 3; ++ic) {
            #pragma unroll
            for (int kh = 0; kh < 3; ++kh) {
                #pragma unroll
                for (int kw = 0; kw < 3; ++kw) {
                    const int pos = (ic * 3 + kh) * 3 + kw;
                    const float xv = sx[ic * 1024 + xb + kh * 32 + kw];
                    const float* wrow = wt + pos * 16;  // uniform -> s_load
                    #pragma unroll
                    for (int oc = 0; oc < 16; ++oc)
                        acc[oc] = fmaf(xv, wrow[oc], acc[oc]);
                }
            }
        }

        if (active) {
            #pragma unroll
            for (int oc = 0; oc < 16; ++oc) {
                const float y = acc[oc];
                const float r = fmaxf(y, 0.f) * fminf(y + 3.f, 6.f) * (1.f / 6.f);
                outn[oc * 900 + p] = r;
            }
        }
    }
}

extern "C" void kernel_launch(void* const* d_in, const int* in_sizes, int n_in,
                              void* d_out, int out_size, void* d_ws, size_t ws_size,
                              hipStream_t stream) {
    const float* x    = (const float*)d_in[0];
    const float* w    = (const float*)d_in[1];
    const float* bias = (const float*)d_in[2];
    float* out        = (float*)d_out;
    float* wt         = (float*)d_ws;   // 448 floats

    prep_weights<<<1, 512, 0, stream>>>(w, bias, wt);

    const int N = in_sizes[0] / (3 * 32 * 32);  // 4096
    conv3x3_hswish<<<N, 256, 0, stream>>>(x, wt, out);
}

// Round 3
// 290.444 us; speedup vs baseline: 3.9872x; 1.0751x over previous
//
#include <hip/hip_runtime.h>

// 3x3 valid conv (NCHW/OIHW) + bias + relu(y)*min(y+3,6)/6, fp32.
// x: (N=4096, C=3, 32, 32), w: (16, 3, 3, 3), out: (N, 16, 30, 30).
//
// Round 3 design:
//  - prep kernel transposes weights to wt[pos][16] + bias in d_ws; the hot
//    loop reads them at wave-uniform addresses -> s_load_dwordx16 (SMEM pipe,
//    zero VGPR cost).
//  - main kernel: ONE PIXEL PER THREAD, 960-thread blocks (15 waves), one
//    image per block, single pass. vs round 2's 256-thr x 4 sequential
//    passes this cuts s_load traffic 4x (27 vs 108 per wave), removes 3x
//    redundant acc-init/addressing, and drops dead-lane waste from 12% to
//    ~6% (one mostly-idle wave of 15).
//  - __launch_bounds__(960, 8): 8 waves/SIMD -> VGPR capped at 64, so
//    2 blocks (30 waves) co-resident per CU. Live set ~34 regs, no spill.

__global__ void prep_weights(const float* __restrict__ w,
                             const float* __restrict__ bias,
                             float* __restrict__ wt) {
    const int i = threadIdx.x;
    if (i < 432) {
        const int oc = i / 27;
        const int pos = i - oc * 27;
        wt[pos * 16 + oc] = w[i];          // wt[27][16]
    }
    if (i < 16) wt[432 + i] = bias[i];
}

__global__ __launch_bounds__(960, 8) void conv3x3_hswish(
    const float* __restrict__ x,
    const float* __restrict__ wt,   // [27][16] weights, then [16] bias
    float* __restrict__ out)
{
    const int n = blockIdx.x;
    const int tid = threadIdx.x;

    __shared__ __align__(16) float sx[3 * 32 * 32];  // 12 KB image

    // Stage input image: 768 float4 loads, threads 0..767.
    if (tid < 768) {
        const float4* xg = (const float4*)(x + (size_t)n * 3072);
        ((float4*)sx)[tid] = xg[tid];
    }
    __syncthreads();

    // One output pixel per thread (p = oh*30+ow), 900 active of 960.
    const int p = tid;
    const bool active = (p < 900);
    const int pc = active ? p : 899;
    const int oh = pc / 30;
    const int ow = pc - oh * 30;
    const int xb = oh * 32 + ow;

    float acc[16];
    #pragma unroll
    for (int oc = 0; oc < 16; ++oc) acc[oc] = wt[432 + oc];  // bias (s_load)

    #pragma unroll
    for (int ic = 0; ic < 3; ++ic) {
        #pragma unroll
        for (int kh = 0; kh < 3; ++kh) {
            #pragma unroll
            for (int kw = 0; kw < 3; ++kw) {
                const int pos = (ic * 3 + kh) * 3 + kw;
                const float xv = sx[ic * 1024 + xb + kh * 32 + kw];
                const float* wrow = wt + pos * 16;  // uniform -> s_load_x16
                #pragma unroll
                for (int oc = 0; oc < 16; ++oc)
                    acc[oc] = fmaf(xv, wrow[oc], acc[oc]);
            }
        }
    }

    if (active) {
        float* outn = out + (size_t)n * 14400;
        #pragma unroll
        for (int oc = 0; oc < 16; ++oc) {
            const float y = acc[oc];
            // relu(y) * min(y+3,6)/6 == max(y,0) * min(y/6 + 0.5, 1)
            const float r = fmaxf(y, 0.f) * fminf(fmaf(y, 1.f / 6.f, 0.5f), 1.f);
            outn[oc * 900 + p] = r;
        }
    }
}

extern "C" void kernel_launch(void* const* d_in, const int* in_sizes, int n_in,
                              void* d_out, int out_size, void* d_ws, size_t ws_size,
                              hipStream_t stream) {
    const float* x    = (const float*)d_in[0];
    const float* w    = (const float*)d_in[1];
    const float* bias = (const float*)d_in[2];
    float* out        = (float*)d_out;
    float* wt         = (float*)d_ws;   // 448 floats

    prep_weights<<<1, 512, 0, stream>>>(w, bias, wt);

    const int N = in_sizes[0] / (3 * 32 * 32);  // 4096
    conv3x3_hswish<<<N, 960, 0, stream>>>(x, wt, out);
}

// Round 4
// 288.086 us; speedup vs baseline: 4.0198x; 1.0082x over previous
//
#include <hip/hip_runtime.h>

// 3x3 valid conv (NCHW/OIHW) + bias + relu(y)*min(y+3,6)/6, fp32.
// x: (N=4096, C=3, 32, 32), w: (16, 3, 3, 3), out: (N, 16, 30, 30).
//
// Round 4 design:
//  - NO global memory in the hot loop. Weights transposed into LDS sw[27][16]
//    per block (prep kernel + d_ws eliminated); hot loop reads them as
//    uniform-address ds_read_b128 broadcasts (conflict-free). Theory: R2/R3's
//    invariant ~140us came from the compiler emitting per-lane global_load
//    broadcasts for the "uniform" wt reads (432 VMEM instrs/wave).
//  - 4 pixels/thread strided by 256 (p = tid + k*256): stride-1 LDS x-reads
//    across lanes (2-way alias = free) and coalesced stores; 64 accs live.
//  - position loop is #pragma unroll 1 (dynamic) with an LDS x-offset table,
//    so only ONE position's 16 weight regs are live at a time -> ~110 VGPR,
//    no round-1 spill blowup. __launch_bounds__(256,4) caps at 128.

__global__ __launch_bounds__(256, 4) void conv3x3_hswish(
    const float* __restrict__ x,
    const float* __restrict__ w,
    const float* __restrict__ bias,
    float* __restrict__ out)
{
    const int n = blockIdx.x;
    const int tid = threadIdx.x;

    __shared__ __align__(16) float sx[3072];   // image, 12 KB
    __shared__ __align__(16) float sw[432];    // [pos][16] weights
    __shared__ __align__(16) float sb[16];     // bias
    __shared__ int sxoff[27];                  // pos -> x offset

    // Stage image: 768 float4s, 3 per thread.
    {
        const float4* xg = (const float4*)(x + (size_t)n * 3072);
        float4* s4 = (float4*)sx;
        #pragma unroll
        for (int i = 0; i < 3; ++i) s4[tid + i * 256] = xg[tid + i * 256];
    }
    // Stage weights transposed: sw[pos*16+oc] = w[oc*27+pos].
    for (int i = tid; i < 432; i += 256) {
        const int oc = i / 27, pos = i - oc * 27;
        sw[pos * 16 + oc] = w[i];
    }
    if (tid < 16) sb[tid] = bias[tid];
    if (tid < 27) {
        const int ic = tid / 9, r = tid - ic * 9, kh = r / 3, kw = r - kh * 3;
        sxoff[tid] = ic * 1024 + kh * 32 + kw;
    }
    __syncthreads();

    // Pixel k of this thread: p = tid + k*256 (flattened oh*30+ow), <900.
    int xb[4];
    #pragma unroll
    for (int k = 0; k < 4; ++k) {
        const int p = tid + k * 256;
        const int pc = p < 900 ? p : 899;   // dead slots clamp reads
        const int oh = pc / 30;
        xb[k] = oh * 32 + (pc - oh * 30);
    }

    float acc[4][16];
    #pragma unroll
    for (int k = 0; k < 4; ++k)
        #pragma unroll
        for (int oc = 0; oc < 16; ++oc) acc[k][oc] = 0.f;

    #pragma unroll 1
    for (int pos = 0; pos < 27; ++pos) {
        const int xoff = sxoff[pos];
        const float4* wv = (const float4*)(sw + pos * 16);
        const float4 w0 = wv[0];
        const float4 w1 = wv[1];
        const float4 w2 = wv[2];
        const float4 w3 = wv[3];
        #pragma unroll
        for (int k = 0; k < 4; ++k) {
            const float xv = sx[xoff + xb[k]];
            acc[k][0]  = fmaf(xv, w0.x, acc[k][0]);
            acc[k][1]  = fmaf(xv, w0.y, acc[k][1]);
            acc[k][2]  = fmaf(xv, w0.z, acc[k][2]);
            acc[k][3]  = fmaf(xv, w0.w, acc[k][3]);
            acc[k][4]  = fmaf(xv, w1.x, acc[k][4]);
            acc[k][5]  = fmaf(xv, w1.y, acc[k][5]);
            acc[k][6]  = fmaf(xv, w1.z, acc[k][6]);
            acc[k][7]  = fmaf(xv, w1.w, acc[k][7]);
            acc[k][8]  = fmaf(xv, w2.x, acc[k][8]);
            acc[k][9]  = fmaf(xv, w2.y, acc[k][9]);
            acc[k][10] = fmaf(xv, w2.z, acc[k][10]);
            acc[k][11] = fmaf(xv, w2.w, acc[k][11]);
            acc[k][12] = fmaf(xv, w3.x, acc[k][12]);
            acc[k][13] = fmaf(xv, w3.y, acc[k][13]);
            acc[k][14] = fmaf(xv, w3.z, acc[k][14]);
            acc[k][15] = fmaf(xv, w3.w, acc[k][15]);
        }
    }

    // Epilogue: bias + hardswish*relu, coalesced scalar stores.
    float* outn = out + (size_t)n * 14400;
    const float4 bb0 = ((const float4*)sb)[0];
    const float4 bb1 = ((const float4*)sb)[1];
    const float4 bb2 = ((const float4*)sb)[2];
    const float4 bb3 = ((const float4*)sb)[3];
    const float bb[16] = {bb0.x, bb0.y, bb0.z, bb0.w, bb1.x, bb1.y, bb1.z, bb1.w,
                          bb2.x, bb2.y, bb2.z, bb2.w, bb3.x, bb3.y, bb3.z, bb3.w};

    #pragma unroll
    for (int k = 0; k < 4; ++k) {
        const int p = tid + k * 256;
        if (p < 900) {
            #pragma unroll
            for (int oc = 0; oc < 16; ++oc) {
                const float y = acc[k][oc] + bb[oc];
                // relu(y) * min(y+3,6)/6 == max(y,0) * min(y/6+0.5, 1)
                const float r = fmaxf(y, 0.f) * fminf(fmaf(y, 1.f / 6.f, 0.5f), 1.f);
                outn[oc * 900 + p] = r;
            }
        }
    }
}

extern "C" void kernel_launch(void* const* d_in, const int* in_sizes, int n_in,
                              void* d_out, int out_size, void* d_ws, size_t ws_size,
                              hipStream_t stream) {
    const float* x    = (const float*)d_in[0];
    const float* w    = (const float*)d_in[1];
    const float* bias = (const float*)d_in[2];
    float* out        = (float*)d_out;

    const int N = in_sizes[0] / (3 * 32 * 32);  // 4096
    conv3x3_hswish<<<N, 256, 0, stream>>>(x, w, bias, out);
}